// Round 9
// baseline (134.177 us; speedup 1.0000x reference)
//
#include <hip/hip_runtime.h>
#include <stdint.h>

#define B_ 2
#define T_ 2048
#define C_ 1024
#define H_ 16
#define D_ 64
#define M_ (B_*T_)
#define BHTD_ (B_*H_*T_*D_)

typedef __bf16 bf16x8 __attribute__((ext_vector_type(8)));
typedef __bf16 bf16x4 __attribute__((ext_vector_type(4)));
typedef __bf16 bf16x2 __attribute__((ext_vector_type(2)));
typedef float f32x4 __attribute__((ext_vector_type(4)));
typedef float f32x16 __attribute__((ext_vector_type(16)));

static __device__ __forceinline__ unsigned short f32_bf16(float f) {
    unsigned int u = __float_as_uint(f);
    u += 0x7FFFu + ((u >> 16) & 1u);   // round-to-nearest-even
    return (unsigned short)(u >> 16);
}

static __device__ __forceinline__ int pack_bf16_2(float a, float b) {
    bf16x2 v = {(__bf16)a, (__bf16)b};
    return __builtin_bit_cast(int, v);
}

// ---------------- cast f32 -> bf16 (vectorized) ----------------
__global__ void cast_kernel(const float* __restrict__ in, unsigned short* __restrict__ out, int n) {
    int i = (blockIdx.x * 256 + threadIdx.x) * 4;
    if (i >= n) return;
    float4 f = *(const float4*)(in + i);
    ushort4 o;
    o.x = f32_bf16(f.x); o.y = f32_bf16(f.y); o.z = f32_bf16(f.z); o.w = f32_bf16(f.w);
    *(ushort4*)(out + i) = o;
}

// ---------------- transpose+cast: W [K][N] f32 -> Wt [N][K] bf16 ----------------
__global__ void transpose_cast_kernel(const float* __restrict__ W, unsigned short* __restrict__ Wt,
                                      int K, int N) {
    __shared__ float tile[32][33];
    int n0 = blockIdx.x * 32, k0 = blockIdx.y * 32;
    int tx = threadIdx.x, ty = threadIdx.y;
    #pragma unroll
    for (int j = 0; j < 32; j += 8)
        tile[ty + j][tx] = W[(size_t)(k0 + ty + j) * N + n0 + tx];
    __syncthreads();
    #pragma unroll
    for (int j = 0; j < 32; j += 8)
        Wt[(size_t)(n0 + ty + j) * K + k0 + tx] = f32_bf16(tile[tx][ty + j]);
}

// ---------------- GEMM (unchanged round-8 2-phase dbuf gll staging) ----------------
template<int EPI>
__global__ __launch_bounds__(256) void gemm_bt(
    const unsigned short* __restrict__ A,
    const unsigned short* __restrict__ Bt,
    const float* __restrict__ bias,
    unsigned short* __restrict__ out_bf16,
    float* __restrict__ out_f32,
    int M, int N, int K)
{
    __shared__ unsigned short As[2][128 * 32];
    __shared__ unsigned short Bs[2][128 * 32];
    int tid = threadIdx.x;
    int lane = tid & 63, wid = tid >> 6;
    int fr = lane & 15, fg = lane >> 4;
    int row0 = blockIdx.x * 128, col0 = blockIdx.y * 128;
    int wm = (wid >> 1) * 64, wn = (wid & 1) * 64;

    f32x4 acc[4][4];
    #pragma unroll
    for (int i = 0; i < 4; ++i)
        #pragma unroll
        for (int j = 0; j < 4; ++j)
            acc[i][j] = (f32x4){0.f, 0.f, 0.f, 0.f};

    const int srw = lane >> 2;
    const int scl = (lane & 3) * 8;
    const int c0 = wid * 2, c1 = wid * 2 + 1;

    auto stage = [&](int buf, int k0) {
        __builtin_amdgcn_global_load_lds(
            (const __attribute__((address_space(1))) void*)(A + (size_t)(row0 + c0 * 16 + srw) * K + k0 + scl),
            (__attribute__((address_space(3))) void*)(As[buf] + c0 * 512), 16, 0, 0);
        __builtin_amdgcn_global_load_lds(
            (const __attribute__((address_space(1))) void*)(A + (size_t)(row0 + c1 * 16 + srw) * K + k0 + scl),
            (__attribute__((address_space(3))) void*)(As[buf] + c1 * 512), 16, 0, 0);
        __builtin_amdgcn_global_load_lds(
            (const __attribute__((address_space(1))) void*)(Bt + (size_t)(col0 + c0 * 16 + srw) * K + k0 + scl),
            (__attribute__((address_space(3))) void*)(Bs[buf] + c0 * 512), 16, 0, 0);
        __builtin_amdgcn_global_load_lds(
            (const __attribute__((address_space(1))) void*)(Bt + (size_t)(col0 + c1 * 16 + srw) * K + k0 + scl),
            (__attribute__((address_space(3))) void*)(Bs[buf] + c1 * 512), 16, 0, 0);
    };

    stage(0, 0);
    __syncthreads();

    int cur = 0;
    for (int k0 = 0; k0 < K; k0 += 32) {
        if (k0 + 32 < K) stage(cur ^ 1, k0 + 32);

        bf16x8 af[4], bfr[4];
        #pragma unroll
        for (int i = 0; i < 4; ++i) {
            af[i]  = *(const bf16x8*)(As[cur] + (wm + i * 16 + fr) * 32 + fg * 8);
            bfr[i] = *(const bf16x8*)(Bs[cur] + (wn + i * 16 + fr) * 32 + fg * 8);
        }
        #pragma unroll
        for (int mi = 0; mi < 4; ++mi)
            #pragma unroll
            for (int ni = 0; ni < 4; ++ni)
                acc[mi][ni] = __builtin_amdgcn_mfma_f32_16x16x32_bf16(af[mi], bfr[ni], acc[mi][ni], 0, 0, 0);

        __syncthreads();
        cur ^= 1;
    }

    #pragma unroll
    for (int mi = 0; mi < 4; ++mi) {
        int rowb = row0 + wm + mi * 16 + fg * 4;
        #pragma unroll
        for (int ni = 0; ni < 4; ++ni) {
            int col = col0 + wn + ni * 16 + fr;
            float bv = bias[col];
            #pragma unroll
            for (int r = 0; r < 4; ++r) {
                float v = acc[mi][ni][r] + bv;
                int rr = rowb + r;
                if (EPI == 0) {
                    int part = col >> 10, c = col & 1023;
                    int h = c >> 6, d = c & 63;
                    int b = rr >> 11, t = rr & 2047;
                    if (part == 0) v *= 0.18033688011112042f;   // fold log2(e)/sqrt(D) into Q
                    size_t idx;
                    if (part == 2)
                        idx = (size_t)2 * BHTD_ + ((size_t)(b * H_ + h) * D_ + d) * T_ + t;
                    else
                        idx = (size_t)part * BHTD_ + ((size_t)(b * H_ + h) * T_ + t) * D_ + d;
                    out_bf16[idx] = f32_bf16(v);
                } else {
                    out_f32[(size_t)rr * N + col] = v;
                }
            }
        }
    }
}

// ---------------- causal flash attention v9: 32x32 MFMA, in-register P ----------------
// 1024 blocks x 128 threads (2 waves x 32 q rows; 64-row chunk per block).
// Balanced grid: per XCD 4 heads x 32 chunks, 4-group complementary chunk map ->
// exactly 66 KV-tile-units per CU for any period-32 block->CU assignment.
// S^T = mfma_32x32x16(K, Q): lane holds full P row (q = lane&31); P -> PV B-frag
// via 4 pack_bf16 + 2 permlane32_swap per 16-kv step (no P LDS at all).
// K/V^T staged via global_load_lds with inverse-swizzled source (rule #21),
// double-buffered, prefetch t+1 issued before compute of t. LDS 32 KB/block.
__global__ __launch_bounds__(128) void attn_kernel(
    const unsigned short* __restrict__ qg,
    const unsigned short* __restrict__ kg,
    const unsigned short* __restrict__ vtg,  // [bh][D][T]
    unsigned short* __restrict__ y)
{
    const int id = blockIdx.x;
    const int xcd = id & 7, j = id >> 3;
    const int c = j & 31, g = j >> 5;
    int chunk;
    if      (g == 0) chunk = 31 - c;
    else if (g == 1) chunk = c;
    else if (g == 2) chunk = (15 - c) & 31;
    else             chunk = (c + 16) & 31;
    const int bh = xcd * 4 + (c >> 3);
    const int b = bh >> 4, h = bh & 15;
    const int tid = threadIdx.x, wid = tid >> 6, lane = tid & 63;
    const int lq = lane & 31, hi = lane >> 5;

    const unsigned short* qp = qg + (size_t)bh * (T_ * D_);
    const char* kpB = (const char*)(kg + (size_t)bh * (T_ * D_));
    const char* vpB = (const char*)(vtg + (size_t)bh * (D_ * T_));

    __shared__ __align__(16) char Ks[2][8192];   // [kv][d] bf16, 128B rows, XOR-swizzled
    __shared__ __align__(16) char Vs[2][8192];   // [d][kv] bf16, 128B rows, XOR-swizzled

    const int r0 = chunk * 64 + wid * 32;
    const int ntk = chunk + 1;

    // Q fragments (pre-scaled by log2e/sqrt(D) in GEMM epilogue): B-operand of mfma(K,Q)
    bf16x8 qf[4];
    #pragma unroll
    for (int ds = 0; ds < 4; ++ds)
        qf[ds] = *(const bf16x8*)(qp + (size_t)(r0 + lq) * D_ + ds * 16 + hi * 8);

    f32x16 oT0, oT1;
    #pragma unroll
    for (int e = 0; e < 16; ++e) { oT0[e] = 0.f; oT1[e] = 0.f; }
    float lrun = 0.f;

    // staging geometry (gll: LDS linear dest, inverse-swizzled per-lane source)
    const int srow8 = lane >> 3;           // row within 8-row / 1KB gll chunk
    const int scol  = (lane & 7) * 16;     // byte col within 128B row
    const int ssw   = srow8 << 4;          // swizzle for this lane's row

    auto stage = [&](int buf, int kv0) {
        #pragma unroll
        for (int blk = 0; blk < 4; ++blk) {
            const int rbase = wid * 32 + blk * 8;
            __builtin_amdgcn_global_load_lds(
                (const __attribute__((address_space(1))) void*)
                    (kpB + (size_t)(kv0 + rbase + srow8) * 128 + (scol ^ ssw)),
                (__attribute__((address_space(3))) void*)(Ks[buf] + rbase * 128), 16, 0, 0);
            __builtin_amdgcn_global_load_lds(
                (const __attribute__((address_space(1))) void*)
                    (vpB + (size_t)(rbase + srow8) * 4096 + kv0 * 2 + (scol ^ ssw)),
                (__attribute__((address_space(3))) void*)(Vs[buf] + rbase * 128), 16, 0, 0);
        }
    };

    // P -> PV B-frag: 4 packs + 2 permlane32_swap (D[32:63] <-> S[0:31]) per 16-kv step.
    // g4a = 0 for kv_local 0..15, g4a = 2 for 16..31 of a 32-kv subtile.
    auto make_pb = [&](const f32x16& p, int g4a) -> bf16x8 {
        int A0 = pack_bf16_2(p[g4a * 4 + 0], p[g4a * 4 + 1]);
        int A1 = pack_bf16_2(p[g4a * 4 + 2], p[g4a * 4 + 3]);
        int B0 = pack_bf16_2(p[g4a * 4 + 4], p[g4a * 4 + 5]);
        int B1 = pack_bf16_2(p[g4a * 4 + 6], p[g4a * 4 + 7]);
        auto ra = __builtin_amdgcn_permlane32_swap(A0, B0, false, false);
        auto rb = __builtin_amdgcn_permlane32_swap(A1, B1, false, false);
        int4 w;
        w.x = ra[0]; w.y = rb[0]; w.z = ra[1]; w.w = rb[1];
        return __builtin_bit_cast(bf16x8, w);
    };

    stage(0, 0);
    __syncthreads();

    const int lsw = (lq & 7) << 4;   // read-side swizzle (row & 7 == lq & 7 for our rows)
    int cur = 0;
    for (int t = 0; t < ntk; ++t) {
        const int kv0 = t * 64;
        if (t + 1 < ntk) stage(cur ^ 1, kv0 + 64);   // prefetch under compute

        const char* Kb = Ks[cur];
        const char* Vb = Vs[cur];
        const bool diag = (t == chunk);
        const bool do_n1 = !(diag && wid == 0);      // wave0's upper 32 kv fully masked on diag

        // ---- S^T = mfma(K, Q): 2 kv-subtiles x 4 d-steps ----
        f32x16 s0, s1;
        #pragma unroll
        for (int e = 0; e < 16; ++e) { s0[e] = 0.f; s1[e] = 0.f; }
        #pragma unroll
        for (int ds = 0; ds < 4; ++ds) {
            bf16x8 kf = *(const bf16x8*)(Kb + lq * 128 + ((ds * 32 + hi * 16) ^ lsw));
            s0 = __builtin_amdgcn_mfma_f32_32x32x16_bf16(kf, qf[ds], s0, 0, 0, 0);
        }
        if (do_n1) {
            #pragma unroll
            for (int ds = 0; ds < 4; ++ds) {
                bf16x8 kf = *(const bf16x8*)(Kb + (32 + lq) * 128 + ((ds * 32 + hi * 16) ^ lsw));
                s1 = __builtin_amdgcn_mfma_f32_32x32x16_bf16(kf, qf[ds], s1, 0, 0, 0);
            }
        }

        // ---- V^T A-frags (issue early; land under softmax VALU) ----
        bf16x8 vf[2][4];
        #pragma unroll
        for (int dd = 0; dd < 2; ++dd)
            #pragma unroll
            for (int st = 0; st < 2; ++st)
                vf[dd][st] = *(const bf16x8*)(Vb + (dd * 32 + lq) * 128 +
                                              ((st * 32 + hi * 16) ^ lsw));
        if (do_n1) {
            #pragma unroll
            for (int dd = 0; dd < 2; ++dd)
                #pragma unroll
                for (int st = 2; st < 4; ++st)
                    vf[dd][st] = *(const bf16x8*)(Vb + (dd * 32 + lq) * 128 +
                                                  ((st * 32 + hi * 16) ^ lsw));
        }

        // ---- no-max softmax (C layout: kv_local = (e&3) + 8*(e>>2) + 4*hi) ----
        const int qrow = r0 + lq;
        if (diag && wid == 0) {
            #pragma unroll
            for (int e = 0; e < 16; ++e) {
                const int kvl = (e & 3) + ((e >> 2) << 3) + hi * 4;
                s0[e] = exp2f((kv0 + kvl <= qrow) ? s0[e] : -1e30f);
            }
        } else {
            #pragma unroll
            for (int e = 0; e < 16; ++e) s0[e] = exp2f(s0[e]);
        }
        {
            float a0 = (s0[0] + s0[1]) + (s0[2] + s0[3]);
            float a1 = (s0[4] + s0[5]) + (s0[6] + s0[7]);
            float a2 = (s0[8] + s0[9]) + (s0[10] + s0[11]);
            float a3 = (s0[12] + s0[13]) + (s0[14] + s0[15]);
            lrun += (a0 + a1) + (a2 + a3);
        }
        if (do_n1) {
            if (diag) {   // here wid == 1: mask subtile n=1
                #pragma unroll
                for (int e = 0; e < 16; ++e) {
                    const int kvl = 32 + (e & 3) + ((e >> 2) << 3) + hi * 4;
                    s1[e] = exp2f((kv0 + kvl <= qrow) ? s1[e] : -1e30f);
                }
            } else {
                #pragma unroll
                for (int e = 0; e < 16; ++e) s1[e] = exp2f(s1[e]);
            }
            float a0 = (s1[0] + s1[1]) + (s1[2] + s1[3]);
            float a1 = (s1[4] + s1[5]) + (s1[6] + s1[7]);
            float a2 = (s1[8] + s1[9]) + (s1[10] + s1[11]);
            float a3 = (s1[12] + s1[13]) + (s1[14] + s1[15]);
            lrun += (a0 + a1) + (a2 + a3);
        }

        // ---- O^T += V^T P^T : in-register P via pack+permlane ----
        {
            bf16x8 pb = make_pb(s0, 0);
            oT0 = __builtin_amdgcn_mfma_f32_32x32x16_bf16(vf[0][0], pb, oT0, 0, 0, 0);
            oT1 = __builtin_amdgcn_mfma_f32_32x32x16_bf16(vf[1][0], pb, oT1, 0, 0, 0);
            pb = make_pb(s0, 2);
            oT0 = __builtin_amdgcn_mfma_f32_32x32x16_bf16(vf[0][1], pb, oT0, 0, 0, 0);
            oT1 = __builtin_amdgcn_mfma_f32_32x32x16_bf16(vf[1][1], pb, oT1, 0, 0, 0);
        }
        if (do_n1) {
            bf16x8 pb = make_pb(s1, 0);
            oT0 = __builtin_amdgcn_mfma_f32_32x32x16_bf16(vf[0][2], pb, oT0, 0, 0, 0);
            oT1 = __builtin_amdgcn_mfma_f32_32x32x16_bf16(vf[1][2], pb, oT1, 0, 0, 0);
            pb = make_pb(s1, 2);
            oT0 = __builtin_amdgcn_mfma_f32_32x32x16_bf16(vf[0][3], pb, oT0, 0, 0, 0);
            oT1 = __builtin_amdgcn_mfma_f32_32x32x16_bf16(vf[1][3], pb, oT1, 0, 0, 0);
        }

        __syncthreads();   // drains prefetch gll + all waves done with cur buffer
        cur ^= 1;
    }

    // ---- epilogue: l reduce across hi halves (each q row lives in 2 lanes) ----
    const float ls = lrun + __shfl_xor(lrun, 32);
    const float inv = 1.f / ls;
    const int trow = r0 + lq;
    unsigned short* yrow = y + ((size_t)b * T_ + trow) * C_ + h * 64;
    #pragma unroll
    for (int dd = 0; dd < 2; ++dd) {
        const f32x16& o = dd ? oT1 : oT0;
        #pragma unroll
        for (int g4 = 0; g4 < 4; ++g4) {
            bf16x4 ov = {(__bf16)(o[g4 * 4 + 0] * inv), (__bf16)(o[g4 * 4 + 1] * inv),
                         (__bf16)(o[g4 * 4 + 2] * inv), (__bf16)(o[g4 * 4 + 3] * inv)};
            *(uint2*)(yrow + dd * 32 + g4 * 8 + hi * 4) = __builtin_bit_cast(uint2, ov);
        }
    }
}

// ---------------- launch ----------------
extern "C" void kernel_launch(void* const* d_in, const int* in_sizes, int n_in,
                              void* d_out, int out_size, void* d_ws, size_t ws_size,
                              hipStream_t stream) {
    const float* x     = (const float*)d_in[0];
    const float* Wqkv  = (const float*)d_in[1];
    const float* bqkv  = (const float*)d_in[2];
    const float* Wproj = (const float*)d_in[3];
    const float* bproj = (const float*)d_in[4];
    float* out = (float*)d_out;

    char* ws = (char*)d_ws;
    unsigned short* x_bf    = (unsigned short*)(ws);                 //  8 MB
    unsigned short* wqkv_t  = (unsigned short*)(ws + 8388608);       //  6 MB
    unsigned short* wproj_t = (unsigned short*)(ws + 14680064);      //  2 MB
    unsigned short* qkv     = (unsigned short*)(ws + 16777216);      // 24 MB
    unsigned short* ybuf    = (unsigned short*)(ws + 41943040);      //  8 MB

    cast_kernel<<<(M_ * C_) / 4 / 256, 256, 0, stream>>>(x, x_bf, M_ * C_);
    transpose_cast_kernel<<<dim3(3072 / 32, 1024 / 32), dim3(32, 8), 0, stream>>>(Wqkv, wqkv_t, 1024, 3072);
    transpose_cast_kernel<<<dim3(1024 / 32, 1024 / 32), dim3(32, 8), 0, stream>>>(Wproj, wproj_t, 1024, 1024);

    gemm_bt<0><<<dim3(M_ / 128, 3072 / 128), 256, 0, stream>>>(
        x_bf, wqkv_t, bqkv, qkv, nullptr, M_, 3072, 1024);

    attn_kernel<<<dim3(1024), 128, 0, stream>>>(
        qkv, qkv + (size_t)BHTD_, qkv + 2 * (size_t)BHTD_, ybuf);

    gemm_bt<1><<<dim3(M_ / 128, 1024 / 128), 256, 0, stream>>>(
        ybuf, wproj_t, bproj, nullptr, out, M_, 1024, 1024);
}